// Round 1
// baseline (540.662 us; speedup 1.0000x reference)
//
#include <hip/hip_runtime.h>
#include <stdint.h>

#define T_ROWS 1500000
#define N_ROWS 2000000
#define N_SEL  1048576
#define G_CNT  (N_SEL/4)
#define RBITS  8
#define RBINS  256
#define TILE   4096
#define ROUNDS (TILE/64)
#define NBLK   ((N_ROWS + TILE - 1)/TILE)
#define NPASS  7

static_assert((uint64_t)NBLK * TILE >= N_ROWS, "tile coverage");
static_assert(N_ROWS < (1 << 21), "index fits 21 bits");

// code = (~orderable(key) << 21) | index  -> ascending code == descending key, index-asc ties
__global__ void build_codes(const float* __restrict__ nb, uint64_t* __restrict__ codes) {
    int i = blockIdx.x * 256 + threadIdx.x;
    if (i >= N_ROWS) return;
    uint32_t u = __float_as_uint(nb[(size_t)i * 5 + 1]);
    uint32_t ku = (u & 0x80000000u) ? ~u : (u | 0x80000000u); // ascending uint == ascending float (total order)
    uint32_t kd = ~ku;                                        // ascending uint == descending float
    codes[i] = ((uint64_t)kd << 21) | (uint32_t)i;
}

__global__ void radix_hist(const uint64_t* __restrict__ src, uint32_t* __restrict__ gHist, int shift) {
    __shared__ uint32_t h[RBINS];
    const int lane = threadIdx.x;
    for (int d = lane; d < RBINS; d += 64) h[d] = 0;
    __syncthreads();
    const int base = blockIdx.x * TILE;
    for (int r = 0; r < ROUNDS; ++r) {
        int idx = base + r * 64 + lane;
        if (idx < N_ROWS) {
            uint32_t d = (uint32_t)(src[idx] >> shift) & (RBINS - 1);
            atomicAdd(&h[d], 1u);
        }
    }
    __syncthreads();
    for (int d = lane; d < RBINS; d += 64) gHist[(size_t)d * NBLK + blockIdx.x] = h[d];
}

// one block per digit: exclusive scan of gHist row in place, row total -> totals[d]
__global__ void radix_rowscan(uint32_t* __restrict__ gHist, uint32_t* __restrict__ totals) {
    const int d = blockIdx.x;
    const int lane = threadIdx.x;
    uint32_t* row = gHist + (size_t)d * NBLK;
    uint32_t carry = 0;
    for (int b0 = 0; b0 < NBLK; b0 += 64) {
        int i = b0 + lane;
        uint32_t v = (i < NBLK) ? row[i] : 0u;
        uint32_t s = v;
        for (int off = 1; off < 64; off <<= 1) {
            uint32_t t = __shfl_up(s, off, 64);
            if (lane >= off) s += t;
        }
        if (i < NBLK) row[i] = s - v + carry;
        carry += __shfl(s, 63, 64);
    }
    if (lane == 0) totals[d] = carry;
}

__global__ void radix_scatter(const uint64_t* __restrict__ src, uint64_t* __restrict__ dst,
                              const uint32_t* __restrict__ gHist, const uint32_t* __restrict__ totals,
                              int shift) {
    __shared__ uint64_t tileS[TILE];
    __shared__ uint32_t counters[RBINS];
    __shared__ uint32_t writeBase[RBINS];
    __shared__ uint32_t lstart[RBINS];
    const int lane = threadIdx.x;
    const int blk = blockIdx.x;
    const int base = blk * TILE;
    const int tileCount = min(TILE, N_ROWS - base);

    // per-lane 4 digits: d = lane*4+k. Build digitStart (scan of totals),
    // localStart (scan of this tile's counts), writeBase = digitStart + rowPrefix - localStart.
    uint32_t tot[4], rp[4], lc[4];
    uint32_t sumTot = 0, sumLc = 0;
    for (int k = 0; k < 4; ++k) {
        int d = lane * 4 + k;
        tot[k] = totals[d];
        rp[k] = gHist[(size_t)d * NBLK + blk];
        uint32_t nrp = (blk + 1 < NBLK) ? gHist[(size_t)d * NBLK + blk + 1] : tot[k];
        lc[k] = nrp - rp[k];
        sumTot += tot[k]; sumLc += lc[k];
    }
    uint32_t sT = sumTot, sL = sumLc;
    for (int off = 1; off < 64; off <<= 1) {
        uint32_t tT = __shfl_up(sT, off, 64);
        uint32_t tL = __shfl_up(sL, off, 64);
        if (lane >= off) { sT += tT; sL += tL; }
    }
    uint32_t exT = sT - sumTot;
    uint32_t exL = sL - sumLc;
    for (int k = 0; k < 4; ++k) {
        int d = lane * 4 + k;
        writeBase[d] = exT + rp[k] - exL;
        lstart[d] = exL;
        counters[d] = 0;
        exT += tot[k]; exL += lc[k];
    }
    __syncthreads();

    // stable local ranking (wave-ballot multi-split), scatter into LDS at sorted pos
    volatile uint32_t* vcnt = counters;
    const uint64_t below = (lane == 0) ? 0ull : (~0ull >> (64 - lane));
    for (int r = 0; r < ROUNDS; ++r) {
        int idx = base + r * 64 + lane;
        bool active = (idx < N_ROWS);
        uint64_t c = active ? src[idx] : 0ull;
        uint32_t d = (uint32_t)(c >> shift) & (RBINS - 1);
        uint64_t m = __ballot(active ? 1 : 0);
        #pragma unroll
        for (int b = 0; b < RBITS; ++b) {
            uint64_t bb = __ballot((active && ((d >> b) & 1u)) ? 1 : 0);
            m = ((d >> b) & 1u) ? (m & bb) : (m & ~bb);
        }
        uint32_t rank = (uint32_t)__popcll(m & below);
        uint32_t before = vcnt[d];        // all lanes read first (one wave: program order)
        if (active) {
            tileS[lstart[d] + before + rank] = c;
            if (rank == 0) vcnt[d] = before + (uint32_t)__popcll(m);  // leader per digit
        }
    }
    __syncthreads();

    // coalesced write-out: consecutive sorted positions with same digit -> consecutive global addrs
    for (int r = 0; r < ROUNDS; ++r) {
        int p = r * 64 + lane;
        if (p < tileCount) {
            uint64_t c = tileS[p];
            uint32_t d = (uint32_t)(c >> shift) & (RBINS - 1);
            dst[(size_t)(writeBase[d] + p)] = c;
        }
    }
}

__global__ void finalize(const uint64_t* __restrict__ sorted,
                         const float* __restrict__ td, const float* __restrict__ nb,
                         float* __restrict__ out) {
    int g = blockIdx.x * 256 + threadIdx.x;
    if (g >= G_CNT) return;
    float maxmin = -100000.0f;
    int maxindex = -100;
    const int base = (N_ROWS - N_SEL) + g * 4;
    #pragma unroll
    for (int j = 0; j < 4; ++j) {
        uint64_t c = sorted[base + j];
        int i = (int)(c & 0x1FFFFFu);
        int tp = (int)nb[(size_t)i * 5 + 0];
        float flag = nb[(size_t)i * 5 + 4];
        float f1 = td[(size_t)tp * 4 + 1];
        float f2 = td[(size_t)tp * 4 + 2];
        float f3 = td[(size_t)tp * 4 + 3];
        float mx = fmaxf(f1, fmaxf(f2, f3));
        bool re1 = (flag != 0.0f);
        bool gt = (mx > maxmin);
        if (re1 == gt) { maxmin = mx; maxindex = tp; }
    }
    int mi = maxindex < 0 ? 0 : maxindex;  // clip(maxindex, 0, ...); upper bound never binds
    const float* row = td + (size_t)mi * 4;
    out[(size_t)g * 4 + 0] = row[0];
    out[(size_t)g * 4 + 1] = row[1];
    out[(size_t)g * 4 + 2] = row[2];
    out[(size_t)g * 4 + 3] = row[3];
}

extern "C" void kernel_launch(void* const* d_in, const int* in_sizes, int n_in,
                              void* d_out, int out_size, void* d_ws, size_t ws_size,
                              hipStream_t stream) {
    const float* td = (const float*)d_in[0];
    const float* nb = (const float*)d_in[1];
    float* out = (float*)d_out;
    uint8_t* ws = (uint8_t*)d_ws;
    uint64_t* A = (uint64_t*)(ws);
    uint64_t* B = (uint64_t*)(ws + (size_t)16 * 1024 * 1024);
    uint32_t* gHist = (uint32_t*)(ws + (size_t)32 * 1024 * 1024);
    uint32_t* totals = (uint32_t*)(ws + (size_t)33 * 1024 * 1024);

    build_codes<<<(N_ROWS + 255) / 256, 256, 0, stream>>>(nb, A);
    uint64_t* s = A; uint64_t* d = B;
    for (int p = 0; p < NPASS; ++p) {
        radix_hist<<<NBLK, 64, 0, stream>>>(s, gHist, p * RBITS);
        radix_rowscan<<<RBINS, 64, 0, stream>>>(gHist, totals);
        radix_scatter<<<NBLK, 64, 0, stream>>>(s, d, gHist, totals, p * RBITS);
        uint64_t* t = s; s = d; d = t;
    }
    finalize<<<(G_CNT + 255) / 256, 256, 0, stream>>>(s, td, nb, out);
}

// Round 2
// 207.726 us; speedup vs baseline: 2.6028x; 2.6028x over previous
//
#include <hip/hip_runtime.h>
#include <stdint.h>

#define T_ROWS 1500000
#define N_ROWS 2000000
#define N_SEL  1048576
#define G_CNT  (N_SEL/4)
#define RBITS  8
#define RBINS  256
#define TILE   2048
#define NBLK   ((N_ROWS + TILE - 1)/TILE)     // 977
#define NPASS  4
#define WAVES  4
#define WTILE  (TILE/WAVES)                    // 512 per wave
#define WROUNDS (WTILE/64)                     // 8 rounds per wave

static_assert((uint64_t)NBLK * TILE >= N_ROWS, "tile coverage");

// code = (descending-orderable key << 32) | index. LSD radix over bits 32..63 is
// stable -> ties keep original (index-ascending) order == jnp.argsort(-bt).
__global__ void build_codes(const float* __restrict__ nb, uint64_t* __restrict__ codes) {
    int i = blockIdx.x * 256 + threadIdx.x;
    if (i >= N_ROWS) return;
    uint32_t u = __float_as_uint(nb[(size_t)i * 5 + 1]);
    uint32_t ku = (u & 0x80000000u) ? ~u : (u | 0x80000000u); // ascending uint == ascending float
    uint32_t kd = ~ku;                                        // ascending uint == descending float
    codes[i] = ((uint64_t)kd << 32) | (uint32_t)i;
}

__global__ void radix_hist(const uint64_t* __restrict__ src, uint32_t* __restrict__ gHist, int shift) {
    __shared__ uint32_t h[RBINS];
    const int t = threadIdx.x;
    if (t < RBINS) h[t] = 0;
    __syncthreads();
    const int base = blockIdx.x * TILE;
    #pragma unroll
    for (int r = 0; r < TILE / 256; ++r) {
        int idx = base + r * 256 + t;
        if (idx < N_ROWS) {
            uint32_t d = (uint32_t)(src[idx] >> shift) & (RBINS - 1);
            atomicAdd(&h[d], 1u);
        }
    }
    __syncthreads();
    if (t < RBINS) gHist[(size_t)t * NBLK + blockIdx.x] = h[t];
}

// one block per digit: exclusive scan of gHist row in place, row total -> totals[d]
__global__ void radix_rowscan(uint32_t* __restrict__ gHist, uint32_t* __restrict__ totals) {
    const int d = blockIdx.x;
    const int lane = threadIdx.x;
    uint32_t* row = gHist + (size_t)d * NBLK;
    uint32_t carry = 0;
    for (int b0 = 0; b0 < NBLK; b0 += 64) {
        int i = b0 + lane;
        uint32_t v = (i < NBLK) ? row[i] : 0u;
        uint32_t s = v;
        for (int off = 1; off < 64; off <<= 1) {
            uint32_t t = __shfl_up(s, off, 64);
            if (lane >= off) s += t;
        }
        if (i < NBLK) row[i] = s - v + carry;
        carry += __shfl(s, 63, 64);
    }
    if (lane == 0) totals[d] = carry;
}

__global__ __launch_bounds__(256) void radix_scatter(
        const uint64_t* __restrict__ src, uint64_t* __restrict__ dst,
        const uint32_t* __restrict__ gHist, const uint32_t* __restrict__ totals,
        int shift) {
    __shared__ uint64_t tileS[TILE];          // 16 KB
    __shared__ uint32_t whist[WAVES * RBINS]; // 4 KB  per-wave digit counts
    __shared__ uint32_t counters[WAVES * RBINS]; // 4 KB running write cursors (phase C)
    __shared__ uint32_t writeBase[RBINS];
    __shared__ uint32_t lstart[RBINS];
    const int t = threadIdx.x;
    const int lane = t & 63;
    const int w = t >> 6;
    const int blk = blockIdx.x;
    const int base = blk * TILE;
    const int tileCount = (N_ROWS - base < TILE) ? (N_ROWS - base) : TILE;

    #pragma unroll
    for (int k = 0; k < (WAVES * RBINS) / 256; ++k) whist[k * 256 + t] = 0u;
    __syncthreads();

    // ---- phase A: per-wave digit histogram (ballot match + leader atomicAdd), keys -> regs
    uint64_t creg[WROUNDS];
    const uint64_t below = (lane == 0) ? 0ull : (~0ull >> (64 - lane));
    #pragma unroll
    for (int r = 0; r < WROUNDS; ++r) {
        int idx = base + w * WTILE + r * 64 + lane;
        bool active = (idx < N_ROWS);
        uint64_t c = active ? src[idx] : 0ull;
        creg[r] = c;
        uint32_t d = (uint32_t)(c >> shift) & (RBINS - 1);
        uint64_t m = __ballot(active ? 1 : 0);
        #pragma unroll
        for (int b = 0; b < RBITS; ++b) {
            uint64_t bb = __ballot((active && ((d >> b) & 1u)) ? 1 : 0);
            m = ((d >> b) & 1u) ? (m & bb) : (m & ~bb);
        }
        int leader = __ffsll((unsigned long long)m) - 1;
        if (active && lane == leader)
            atomicAdd(&whist[w * RBINS + d], (uint32_t)__popcll(m));
    }
    __syncthreads();

    // ---- phase B1: wave 0 computes writeBase[d], lstart[d] from gHist/totals
    if (t < 64) {
        uint32_t tot[4], rp[4], lc[4];
        uint32_t sumTot = 0, sumLc = 0;
        #pragma unroll
        for (int k = 0; k < 4; ++k) {
            int d = t * 4 + k;
            tot[k] = totals[d];
            rp[k] = gHist[(size_t)d * NBLK + blk];
            uint32_t nrp = (blk + 1 < NBLK) ? gHist[(size_t)d * NBLK + blk + 1] : tot[k];
            lc[k] = nrp - rp[k];
            sumTot += tot[k]; sumLc += lc[k];
        }
        uint32_t sT = sumTot, sL = sumLc;
        for (int off = 1; off < 64; off <<= 1) {
            uint32_t tT = __shfl_up(sT, off, 64);
            uint32_t tL = __shfl_up(sL, off, 64);
            if (t >= off) { sT += tT; sL += tL; }
        }
        uint32_t exT = sT - sumTot;
        uint32_t exL = sL - sumLc;
        #pragma unroll
        for (int k = 0; k < 4; ++k) {
            int d = t * 4 + k;
            writeBase[d] = exT + rp[k] - exL;
            lstart[d] = exL;
            exT += tot[k]; exL += lc[k];
        }
    }
    __syncthreads();

    // ---- phase B2: per-wave cursors: counters[w][d] = lstart[d] + sum_{w'<w} whist[w'][d]
    {
        uint32_t running = lstart[t & (RBINS - 1)]; // t in [0,256): one digit each
        #pragma unroll
        for (int wv = 0; wv < WAVES; ++wv) {
            counters[wv * RBINS + t] = running;
            running += whist[wv * RBINS + t];
        }
    }
    __syncthreads();

    // ---- phase C: stable rank within wave, scatter to LDS sorted position
    #pragma unroll
    for (int r = 0; r < WROUNDS; ++r) {
        int idx = base + w * WTILE + r * 64 + lane;
        bool active = (idx < N_ROWS);
        uint64_t c = creg[r];
        uint32_t d = (uint32_t)(c >> shift) & (RBINS - 1);
        uint64_t m = __ballot(active ? 1 : 0);
        #pragma unroll
        for (int b = 0; b < RBITS; ++b) {
            uint64_t bb = __ballot((active && ((d >> b) & 1u)) ? 1 : 0);
            m = ((d >> b) & 1u) ? (m & bb) : (m & ~bb);
        }
        int leader = __ffsll((unsigned long long)m) - 1;
        uint32_t rank = (uint32_t)__popcll(m & below);
        uint32_t before = 0;
        if (active && lane == leader)
            before = atomicAdd(&counters[w * RBINS + d], (uint32_t)__popcll(m));
        before = __shfl(before, leader < 0 ? 0 : leader, 64);
        if (active) tileS[before + rank] = c;
    }
    __syncthreads();

    // ---- write-out: consecutive sorted positions share digit -> coalesced segments
    #pragma unroll
    for (int r = 0; r < TILE / 256; ++r) {
        int p = r * 256 + t;
        if (p < tileCount) {
            uint64_t c = tileS[p];
            uint32_t d = (uint32_t)(c >> shift) & (RBINS - 1);
            dst[(size_t)(writeBase[d] + p)] = c;
        }
    }
}

__global__ void finalize(const uint64_t* __restrict__ sorted,
                         const float* __restrict__ td, const float* __restrict__ nb,
                         float* __restrict__ out) {
    int g = blockIdx.x * 256 + threadIdx.x;
    if (g >= G_CNT) return;
    float maxmin = -100000.0f;
    int maxindex = -100;
    const int base = (N_ROWS - N_SEL) + g * 4;
    #pragma unroll
    for (int j = 0; j < 4; ++j) {
        uint64_t c = sorted[base + j];
        int i = (int)(c & 0xFFFFFFFFu);
        int tp = (int)nb[(size_t)i * 5 + 0];
        float flag = nb[(size_t)i * 5 + 4];
        float f1 = td[(size_t)tp * 4 + 1];
        float f2 = td[(size_t)tp * 4 + 2];
        float f3 = td[(size_t)tp * 4 + 3];
        float mx = fmaxf(f1, fmaxf(f2, f3));
        bool re1 = (flag != 0.0f);
        bool gt = (mx > maxmin);
        if (re1 == gt) { maxmin = mx; maxindex = tp; }
    }
    int mi = maxindex < 0 ? 0 : maxindex;  // clip lower bound; upper never binds
    const float4 row = *(const float4*)(td + (size_t)mi * 4);
    *(float4*)(out + (size_t)g * 4) = row;
}

extern "C" void kernel_launch(void* const* d_in, const int* in_sizes, int n_in,
                              void* d_out, int out_size, void* d_ws, size_t ws_size,
                              hipStream_t stream) {
    const float* td = (const float*)d_in[0];
    const float* nb = (const float*)d_in[1];
    float* out = (float*)d_out;
    uint8_t* ws = (uint8_t*)d_ws;
    uint64_t* A = (uint64_t*)(ws);
    uint64_t* B = (uint64_t*)(ws + (size_t)16 * 1024 * 1024);
    uint32_t* gHist = (uint32_t*)(ws + (size_t)32 * 1024 * 1024);
    uint32_t* totals = (uint32_t*)(ws + (size_t)33 * 1024 * 1024 + 64 * 1024);

    build_codes<<<(N_ROWS + 255) / 256, 256, 0, stream>>>(nb, A);
    uint64_t* s = A; uint64_t* d = B;
    for (int p = 0; p < NPASS; ++p) {
        radix_hist<<<NBLK, 256, 0, stream>>>(s, gHist, 32 + p * RBITS);
        radix_rowscan<<<RBINS, 64, 0, stream>>>(gHist, totals);
        radix_scatter<<<NBLK, 256, 0, stream>>>(s, d, gHist, totals, 32 + p * RBITS);
        uint64_t* t = s; s = d; d = t;
    }
    finalize<<<(G_CNT + 255) / 256, 256, 0, stream>>>(s, td, nb, out);
}

// Round 3
// 179.172 us; speedup vs baseline: 3.0176x; 1.1594x over previous
//
#include <hip/hip_runtime.h>
#include <stdint.h>

#define T_ROWS 1500000
#define N_ROWS 2000000
#define N_SEL  1048576
#define G_CNT  (N_SEL/4)
#define RBITS  8
#define RBINS  256
#define TILE   4096
#define NBLK   ((N_ROWS + TILE - 1)/TILE)     // 489
#define NPASS  4
#define THREADS 512
#define WAVES  (THREADS/64)                    // 8
#define WTILE  (TILE/WAVES)                    // 512 per wave
#define WROUNDS (WTILE/64)                     // 8 rounds per wave
#define NB_CODE ((N_ROWS + 255)/256)           // 7813
#define NB_MX   ((T_ROWS + 255)/256)           // 5860

static_assert((uint64_t)NBLK * TILE >= N_ROWS, "tile coverage");
static_assert(T_ROWS < (1 << 21), "tp fits 21 bits");

// code = (descending-orderable key << 32) | (flag!=0 << 21) | tp.
// LSD radix over bits 32..63 is stable -> ties keep original (index-ascending)
// order == jnp.argsort(-bt). Payload carries everything finalize needs, so
// finalize never touches `nb` (kills the 128MB random-gather HBM traffic).
__global__ void build_all(const float* __restrict__ nb, const float* __restrict__ td,
                          uint64_t* __restrict__ codes, float* __restrict__ mxtab) {
    int b = blockIdx.x;
    if (b < NB_CODE) {
        int i = b * 256 + threadIdx.x;
        if (i >= N_ROWS) return;
        const float* row = nb + (size_t)i * 5;
        uint32_t u = __float_as_uint(row[1]);
        uint32_t ku = (u & 0x80000000u) ? ~u : (u | 0x80000000u); // asc uint == asc float
        uint32_t kd = ~ku;                                        // asc uint == desc float
        uint32_t tp = (uint32_t)(int)row[0];                      // exact: ids are integral f32
        uint32_t fl = (row[4] != 0.0f) ? 1u : 0u;
        codes[i] = ((uint64_t)kd << 32) | (fl << 21) | tp;
    } else {
        int t = (b - NB_CODE) * 256 + threadIdx.x;
        if (t >= T_ROWS) return;
        float4 r = *(const float4*)(td + (size_t)t * 4);
        mxtab[t] = fmaxf(r.y, fmaxf(r.z, r.w));
    }
}

__global__ __launch_bounds__(THREADS) void radix_hist(
        const uint64_t* __restrict__ src, uint32_t* __restrict__ gHist, int shift) {
    __shared__ uint32_t h[RBINS];
    const int t = threadIdx.x;
    const int lane = t & 63;
    if (t < RBINS) h[t] = 0;
    __syncthreads();
    const int base = blockIdx.x * TILE;
    #pragma unroll
    for (int r = 0; r < TILE / THREADS; ++r) {
        int idx = base + r * THREADS + t;
        bool active = (idx < N_ROWS);
        uint32_t d = active ? ((uint32_t)(src[idx] >> shift) & (RBINS - 1)) : 0u;
        // ballot-leader count (top-byte pass is exponent-skewed; avoids hot-bin atomics)
        uint64_t m = __ballot(active ? 1 : 0);
        #pragma unroll
        for (int bb = 0; bb < RBITS; ++bb) {
            uint64_t x = __ballot((active && ((d >> bb) & 1u)) ? 1 : 0);
            m = ((d >> bb) & 1u) ? (m & x) : (m & ~x);
        }
        int leader = __ffsll((unsigned long long)m) - 1;
        if (active && lane == leader) atomicAdd(&h[d], (uint32_t)__popcll(m));
    }
    __syncthreads();
    if (t < RBINS) gHist[(size_t)t * NBLK + blockIdx.x] = h[t];
}

// one block per digit: exclusive scan of gHist row in place, row total -> totals[d]
__global__ void radix_rowscan(uint32_t* __restrict__ gHist, uint32_t* __restrict__ totals) {
    const int d = blockIdx.x;
    const int lane = threadIdx.x;
    uint32_t* row = gHist + (size_t)d * NBLK;
    uint32_t carry = 0;
    for (int b0 = 0; b0 < NBLK; b0 += 64) {
        int i = b0 + lane;
        uint32_t v = (i < NBLK) ? row[i] : 0u;
        uint32_t s = v;
        for (int off = 1; off < 64; off <<= 1) {
            uint32_t t = __shfl_up(s, off, 64);
            if (lane >= off) s += t;
        }
        if (i < NBLK) row[i] = s - v + carry;
        carry += __shfl(s, 63, 64);
    }
    if (lane == 0) totals[d] = carry;
}

__global__ __launch_bounds__(THREADS) void radix_scatter(
        const uint64_t* __restrict__ src, uint64_t* __restrict__ dst,
        const uint32_t* __restrict__ gHist, const uint32_t* __restrict__ totals,
        int shift) {
    __shared__ uint64_t tileS[TILE];             // 32 KB
    __shared__ uint32_t whist[WAVES * RBINS];    // 8 KB
    __shared__ uint32_t counters[WAVES * RBINS]; // 8 KB
    __shared__ uint32_t writeBase[RBINS];
    __shared__ uint32_t lstart[RBINS];
    const int t = threadIdx.x;
    const int lane = t & 63;
    const int w = t >> 6;
    const int blk = blockIdx.x;
    const int base = blk * TILE;
    const int tileCount = (N_ROWS - base < TILE) ? (N_ROWS - base) : TILE;

    #pragma unroll
    for (int k = 0; k < (WAVES * RBINS) / THREADS; ++k) whist[k * THREADS + t] = 0u;
    __syncthreads();

    // ---- phase A: per-wave digit histogram (ballot match + leader atomicAdd), keys -> regs
    uint64_t creg[WROUNDS];
    const uint64_t below = (lane == 0) ? 0ull : (~0ull >> (64 - lane));
    #pragma unroll
    for (int r = 0; r < WROUNDS; ++r) {
        int idx = base + w * WTILE + r * 64 + lane;
        bool active = (idx < N_ROWS);
        uint64_t c = active ? src[idx] : 0ull;
        creg[r] = c;
        uint32_t d = (uint32_t)(c >> shift) & (RBINS - 1);
        uint64_t m = __ballot(active ? 1 : 0);
        #pragma unroll
        for (int b = 0; b < RBITS; ++b) {
            uint64_t bb = __ballot((active && ((d >> b) & 1u)) ? 1 : 0);
            m = ((d >> b) & 1u) ? (m & bb) : (m & ~bb);
        }
        int leader = __ffsll((unsigned long long)m) - 1;
        if (active && lane == leader)
            atomicAdd(&whist[w * RBINS + d], (uint32_t)__popcll(m));
    }
    __syncthreads();

    // ---- phase B1: wave 0 computes writeBase[d], lstart[d] from gHist/totals
    if (t < 64) {
        uint32_t tot[4], rp[4], lc[4];
        uint32_t sumTot = 0, sumLc = 0;
        #pragma unroll
        for (int k = 0; k < 4; ++k) {
            int d = t * 4 + k;
            tot[k] = totals[d];
            rp[k] = gHist[(size_t)d * NBLK + blk];
            uint32_t nrp = (blk + 1 < NBLK) ? gHist[(size_t)d * NBLK + blk + 1] : tot[k];
            lc[k] = nrp - rp[k];
            sumTot += tot[k]; sumLc += lc[k];
        }
        uint32_t sT = sumTot, sL = sumLc;
        for (int off = 1; off < 64; off <<= 1) {
            uint32_t tT = __shfl_up(sT, off, 64);
            uint32_t tL = __shfl_up(sL, off, 64);
            if (t >= off) { sT += tT; sL += tL; }
        }
        uint32_t exT = sT - sumTot;
        uint32_t exL = sL - sumLc;
        #pragma unroll
        for (int k = 0; k < 4; ++k) {
            int d = t * 4 + k;
            writeBase[d] = exT + rp[k] - exL;
            lstart[d] = exL;
            exT += tot[k]; exL += lc[k];
        }
    }
    __syncthreads();

    // ---- phase B2: per-wave cursors: counters[w][d] = lstart[d] + sum_{w'<w} whist[w'][d]
    if (t < RBINS) {
        uint32_t running = lstart[t];
        #pragma unroll
        for (int wv = 0; wv < WAVES; ++wv) {
            counters[wv * RBINS + t] = running;
            running += whist[wv * RBINS + t];
        }
    }
    __syncthreads();

    // ---- phase C: stable rank within wave, scatter to LDS sorted position
    #pragma unroll
    for (int r = 0; r < WROUNDS; ++r) {
        int idx = base + w * WTILE + r * 64 + lane;
        bool active = (idx < N_ROWS);
        uint64_t c = creg[r];
        uint32_t d = (uint32_t)(c >> shift) & (RBINS - 1);
        uint64_t m = __ballot(active ? 1 : 0);
        #pragma unroll
        for (int b = 0; b < RBITS; ++b) {
            uint64_t bb = __ballot((active && ((d >> b) & 1u)) ? 1 : 0);
            m = ((d >> b) & 1u) ? (m & bb) : (m & ~bb);
        }
        int leader = __ffsll((unsigned long long)m) - 1;
        int ldr = leader < 0 ? 0 : leader;
        uint32_t rank = (uint32_t)__popcll(m & below);
        uint32_t before = 0;
        if (active && lane == leader)
            before = atomicAdd(&counters[w * RBINS + d], (uint32_t)__popcll(m));
        before = __shfl(before, ldr, 64);
        if (active) tileS[before + rank] = c;
    }
    __syncthreads();

    // ---- write-out: consecutive sorted positions share digit -> coalesced segments
    #pragma unroll
    for (int r = 0; r < TILE / THREADS; ++r) {
        int p = r * THREADS + t;
        if (p < tileCount) {
            uint64_t c = tileS[p];
            uint32_t d = (uint32_t)(c >> shift) & (RBINS - 1);
            dst[(size_t)(writeBase[d] + p)] = c;
        }
    }
}

template <bool USE_MX>
__global__ void finalize_k(const uint64_t* __restrict__ sorted,
                           const float* __restrict__ td, const float* __restrict__ mxtab,
                           float* __restrict__ out) {
    int g = blockIdx.x * 256 + threadIdx.x;
    if (g >= G_CNT) return;
    const ulonglong2* p = (const ulonglong2*)(sorted + (N_ROWS - N_SEL)) + (size_t)g * 2;
    ulonglong2 c01 = p[0];
    ulonglong2 c23 = p[1];
    uint64_t cs[4] = {c01.x, c01.y, c23.x, c23.y};
    float maxmin = -100000.0f;
    int maxindex = -100;
    #pragma unroll
    for (int j = 0; j < 4; ++j) {
        uint32_t pl = (uint32_t)cs[j];
        int tp = (int)(pl & 0x1FFFFFu);
        bool re1 = ((pl >> 21) & 1u) != 0u;
        float mx;
        if (USE_MX) {
            mx = mxtab[tp];
        } else {
            float4 r = *(const float4*)(td + (size_t)tp * 4);
            mx = fmaxf(r.y, fmaxf(r.z, r.w));
        }
        bool gt = (mx > maxmin);
        if (re1 == gt) { maxmin = mx; maxindex = tp; }
    }
    int mi = maxindex < 0 ? 0 : maxindex;  // clip lower bound; upper never binds
    const float4 row = *(const float4*)(td + (size_t)mi * 4);
    *(float4*)(out + (size_t)g * 4) = row;
}

extern "C" void kernel_launch(void* const* d_in, const int* in_sizes, int n_in,
                              void* d_out, int out_size, void* d_ws, size_t ws_size,
                              hipStream_t stream) {
    const float* td = (const float*)d_in[0];
    const float* nb = (const float*)d_in[1];
    float* out = (float*)d_out;
    uint8_t* ws = (uint8_t*)d_ws;

    const size_t SZ_CODES = (size_t)N_ROWS * 8;          // 16,000,000
    const size_t SZ_MX    = (size_t)T_ROWS * 4;          //  6,000,000
    const size_t SZ_HIST  = (size_t)RBINS * NBLK * 4;    //    500,736

    // Preferred layout (needs ~39.3 MB): mxtab | gHist | totals | A | B
    const size_t OFF_MX   = 0;
    const size_t OFF_HIST = 6 * 1024 * 1024;
    const size_t OFF_TOT  = OFF_HIST + 524288;
    const size_t OFF_A    = 8 * 1024 * 1024;
    const size_t OFF_B    = OFF_A + 16 * 1024 * 1024;
    const bool use_mx = (ws_size >= OFF_B + SZ_CODES);

    float* mxtab;
    uint32_t *gHist, *totals;
    uint64_t *A, *B;
    if (use_mx) {
        mxtab  = (float*)(ws + OFF_MX);
        gHist  = (uint32_t*)(ws + OFF_HIST);
        totals = (uint32_t*)(ws + OFF_TOT);
        A      = (uint64_t*)(ws + OFF_A);
        B      = (uint64_t*)(ws + OFF_B);
    } else {
        // Fallback compact layout (~33 MB), finalize computes mx from td directly.
        gHist  = (uint32_t*)(ws);
        totals = (uint32_t*)(ws + 786432);
        A      = (uint64_t*)(ws + 1048576);
        B      = (uint64_t*)(ws + 1048576 + 16777216);
        mxtab  = nullptr;
    }

    if (use_mx) {
        build_all<<<NB_CODE + NB_MX, 256, 0, stream>>>(nb, td, A, mxtab);
    } else {
        build_all<<<NB_CODE, 256, 0, stream>>>(nb, td, A, (float*)out /*unused*/);
    }

    uint64_t* s = A; uint64_t* d = B;
    for (int p = 0; p < NPASS; ++p) {
        radix_hist<<<NBLK, THREADS, 0, stream>>>(s, gHist, 32 + p * RBITS);
        radix_rowscan<<<RBINS, 64, 0, stream>>>(gHist, totals);
        radix_scatter<<<NBLK, THREADS, 0, stream>>>(s, d, gHist, totals, 32 + p * RBITS);
        uint64_t* t = s; s = d; d = t;
    }
    if (use_mx) {
        finalize_k<true><<<(G_CNT + 255) / 256, 256, 0, stream>>>(s, td, mxtab, out);
    } else {
        finalize_k<false><<<(G_CNT + 255) / 256, 256, 0, stream>>>(s, td, nullptr, out);
    }
}

// Round 4
// 174.364 us; speedup vs baseline: 3.1008x; 1.0276x over previous
//
#include <hip/hip_runtime.h>
#include <stdint.h>

#define T_ROWS 1500000
#define N_ROWS 2000000
#define N_SEL  1048576
#define G_CNT  (N_SEL/4)
#define LB     (N_ROWS - N_SEL)
#define TILE   4096
#define NBLK   ((N_ROWS + TILE - 1)/TILE)     // 489
#define THREADS 512
#define WAVES  8
#define WTILE  (TILE/WAVES)                    // 512
#define WROUNDS (WTILE/64)                     // 8
#define GSTRIDE 2048                           // gT row stride (max BINS)
#define NB_MX  ((T_ROWS + THREADS - 1)/THREADS)

static_assert((uint64_t)NBLK * TILE >= N_ROWS, "tile coverage");
static_assert(T_ROWS < (1 << 21), "tp fits 21 bits");
static_assert((LB * 4) % 16 == 0, "finalize uint4 alignment");

// code = (descending-orderable key << 32) | (flag!=0 << 21) | tp.
// LSD radix over bits [32,64) is stable -> ties keep original (index-ascending)
// order == jnp.argsort(-bt). Payload carries everything finalize needs.
// build also produces the pass-0 per-tile histogram (kd already in regs) and mxtab.
__global__ __launch_bounds__(THREADS) void build_all(
        const float* __restrict__ nb, const float* __restrict__ td,
        uint64_t* __restrict__ codes, float* __restrict__ mxtab,
        uint32_t* __restrict__ gT) {
    const int b = blockIdx.x;
    if (b >= NBLK) {
        int i = (b - NBLK) * THREADS + threadIdx.x;
        if (i < T_ROWS) {
            float4 r = *(const float4*)(td + (size_t)i * 4);
            mxtab[i] = fmaxf(r.y, fmaxf(r.z, r.w));
        }
        return;
    }
    __shared__ uint32_t h[2048];
    const int t = threadIdx.x;
    const int lane = t & 63;
    for (int k = t; k < 2048; k += THREADS) h[k] = 0;
    __syncthreads();
    const int base = b * TILE;
    #pragma unroll
    for (int r = 0; r < TILE / THREADS; ++r) {
        int i = base + r * THREADS + t;
        bool active = (i < N_ROWS);
        uint32_t kd = 0;
        if (active) {
            const float* row = nb + (size_t)i * 5;
            uint32_t u = __float_as_uint(row[1]);
            uint32_t ku = (u & 0x80000000u) ? ~u : (u | 0x80000000u); // asc uint == asc float
            kd = ~ku;                                                 // asc uint == desc float
            uint32_t tp = (uint32_t)(int)row[0];                      // exact: integral f32
            uint32_t fl = (row[4] != 0.0f) ? 1u : 0u;
            codes[i] = ((uint64_t)kd << 32) | (fl << 21) | tp;
        }
        uint32_t d = kd & 2047u;           // pass-0 digit (11 bits)
        uint64_t m = __ballot(active ? 1 : 0);
        #pragma unroll
        for (int bb = 0; bb < 11; ++bb) {
            uint64_t x = __ballot((active && ((d >> bb) & 1u)) ? 1 : 0);
            m = ((d >> bb) & 1u) ? (m & x) : (m & ~x);
        }
        int ldr = __ffsll((unsigned long long)m) - 1;
        if (active && lane == ldr) atomicAdd(&h[d], (uint32_t)__popcll(m));
    }
    __syncthreads();
    for (int k = t; k < 2048; k += THREADS) gT[(size_t)b * GSTRIDE + k] = h[k];
}

template <int SHIFT, int BITS>
__global__ __launch_bounds__(THREADS) void radix_hist(
        const uint64_t* __restrict__ src, uint32_t* __restrict__ gT) {
    constexpr int BINS = 1 << BITS;
    __shared__ uint32_t h[BINS];
    const int t = threadIdx.x;
    const int lane = t & 63;
    for (int k = t; k < BINS; k += THREADS) h[k] = 0;
    __syncthreads();
    const int base = blockIdx.x * TILE;
    #pragma unroll
    for (int r = 0; r < TILE / THREADS; ++r) {
        int i = base + r * THREADS + t;
        bool active = (i < N_ROWS);
        uint32_t d = active ? ((uint32_t)(src[i] >> SHIFT) & (BINS - 1)) : 0u;
        uint64_t m = __ballot(active ? 1 : 0);
        #pragma unroll
        for (int bb = 0; bb < BITS; ++bb) {
            uint64_t x = __ballot((active && ((d >> bb) & 1u)) ? 1 : 0);
            m = ((d >> bb) & 1u) ? (m & x) : (m & ~x);
        }
        int ldr = __ffsll((unsigned long long)m) - 1;
        if (active && lane == ldr) atomicAdd(&h[d], (uint32_t)__popcll(m));
    }
    __syncthreads();
    for (int k = t; k < BINS; k += THREADS) gT[(size_t)blockIdx.x * GSTRIDE + k] = h[k];
}

// one block per digit: exclusive scan of gT column d; totals row at NBLK; totals[d]
__global__ void radix_rowscan(uint32_t* __restrict__ gT, uint32_t* __restrict__ totals) {
    const int d = blockIdx.x;
    const int lane = threadIdx.x;
    uint32_t carry = 0;
    for (int b0 = 0; b0 < NBLK; b0 += 64) {
        int i = b0 + lane;
        uint32_t v = (i < NBLK) ? gT[(size_t)i * GSTRIDE + d] : 0u;
        uint32_t s = v;
        for (int off = 1; off < 64; off <<= 1) {
            uint32_t tt = __shfl_up(s, off, 64);
            if (lane >= off) s += tt;
        }
        if (i < NBLK) gT[(size_t)i * GSTRIDE + d] = s - v + carry;
        carry += __shfl(s, 63, 64);
    }
    if (lane == 0) {
        gT[(size_t)NBLK * GSTRIDE + d] = carry;
        totals[d] = carry;
    }
}

template <int SHIFT, int BITS, bool LAST>
__global__ __launch_bounds__(THREADS) void radix_scatter(
        const uint64_t* __restrict__ src, uint64_t* __restrict__ dst,
        uint32_t* __restrict__ dst32,
        const uint32_t* __restrict__ gT, const uint32_t* __restrict__ totals) {
    constexpr int BINS = 1 << BITS;
    constexpr int DPT = BINS / THREADS;              // digits per thread (4 or 2)
    __shared__ uint64_t tileS[TILE];                 // 32 KB
    __shared__ uint32_t cnt16[BINS * (WAVES / 2)];   // u16 pairs: [d][w/2], 32/16 KB
    __shared__ uint32_t writeBase[BINS];
    __shared__ uint32_t wpT[WAVES], wpL[WAVES];
    const int t = threadIdx.x;
    const int lane = t & 63;
    const int w = t >> 6;
    const int blk = blockIdx.x;
    const int base = blk * TILE;
    const int tileCount = (N_ROWS - base < TILE) ? (N_ROWS - base) : TILE;

    for (int k = t; k < BINS * (WAVES / 2); k += THREADS) cnt16[k] = 0u;
    __syncthreads();

    // ---- phase A: per-wave digit counts (ballot match); store (rank,ldr,cnt) per round
    uint64_t creg[WROUNDS];
    uint32_t meta[WROUNDS];
    const uint64_t below = (lane == 0) ? 0ull : (~0ull >> (64 - lane));
    #pragma unroll
    for (int r = 0; r < WROUNDS; ++r) {
        int idx = base + w * WTILE + r * 64 + lane;
        bool active = (idx < N_ROWS);
        uint64_t c = active ? src[idx] : 0ull;
        creg[r] = c;
        uint32_t d = (uint32_t)(c >> SHIFT) & (BINS - 1);
        uint64_t m = __ballot(active ? 1 : 0);
        #pragma unroll
        for (int bb = 0; bb < BITS; ++bb) {
            uint64_t x = __ballot((active && ((d >> bb) & 1u)) ? 1 : 0);
            m = ((d >> bb) & 1u) ? (m & x) : (m & ~x);
        }
        int ldr = __ffsll((unsigned long long)m) - 1;
        uint32_t cnt = (uint32_t)__popcll(m);
        uint32_t rank = (uint32_t)__popcll(m & below);
        bool isldr = active && (lane == ldr);
        meta[r] = rank | ((uint32_t)(ldr < 0 ? 0 : ldr) << 8) | (cnt << 16);
        if (isldr)
            atomicAdd(&cnt16[d * (WAVES / 2) + (w >> 1)], cnt << (16 * (w & 1)));
    }
    __syncthreads();

    // ---- phase B: block scans (totals, local counts) + in-place cursor init
    uint32_t tot[DPT], rp[DPT], lc[DPT];
    uint32_t sumT = 0, sumL = 0;
    #pragma unroll
    for (int k = 0; k < DPT; ++k) {
        int d = t * DPT + k;
        tot[k] = totals[d];
        rp[k] = gT[(size_t)blk * GSTRIDE + d];
        lc[k] = gT[(size_t)(blk + 1) * GSTRIDE + d] - rp[k];
        sumT += tot[k]; sumL += lc[k];
    }
    uint32_t sT = sumT, sL = sumL;
    for (int off = 1; off < 64; off <<= 1) {
        uint32_t aT = __shfl_up(sT, off, 64);
        uint32_t aL = __shfl_up(sL, off, 64);
        if (lane >= off) { sT += aT; sL += aL; }
    }
    if (lane == 63) { wpT[w] = sT; wpL[w] = sL; }
    __syncthreads();
    uint32_t exT = sT - sumT, exL = sL - sumL;
    #pragma unroll
    for (int wv = 0; wv < WAVES; ++wv) if (wv < w) { exT += wpT[wv]; exL += wpL[wv]; }
    #pragma unroll
    for (int k = 0; k < DPT; ++k) {
        int d = t * DPT + k;
        writeBase[d] = exT + rp[k] - exL;
        uint32_t run = exL;   // cursor = tile-local start + cross-wave prefix (u16, <=4096)
        #pragma unroll
        for (int wq = 0; wq < WAVES / 2; ++wq) {
            uint32_t word = cnt16[d * (WAVES / 2) + wq];
            uint32_t c0 = word & 0xFFFFu, c1 = word >> 16;
            cnt16[d * (WAVES / 2) + wq] = run | ((run + c0) << 16);
            run += c0 + c1;
        }
        exT += tot[k]; exL += lc[k];
    }
    __syncthreads();

    // ---- phase C: no ballots — leader atomicAdd on packed cursor, shfl, LDS scatter
    #pragma unroll
    for (int r = 0; r < WROUNDS; ++r) {
        int idx = base + w * WTILE + r * 64 + lane;
        bool active = (idx < N_ROWS);
        uint64_t c = creg[r];
        uint32_t d = (uint32_t)(c >> SHIFT) & (BINS - 1);
        uint32_t mt = meta[r];
        uint32_t rank = mt & 0xFFu;
        int ldr = (int)((mt >> 8) & 0xFFu);
        uint32_t cnt = mt >> 16;
        uint32_t before = 0;
        if (active && lane == ldr) {
            uint32_t old = atomicAdd(&cnt16[d * (WAVES / 2) + (w >> 1)],
                                     cnt << (16 * (w & 1)));
            before = (old >> (16 * (w & 1))) & 0xFFFFu;
        }
        before = __shfl(before, ldr, 64);
        if (active) tileS[before + rank] = c;
    }
    __syncthreads();

    // ---- write-out: consecutive sorted positions share digit -> coalesced segments
    #pragma unroll
    for (int r = 0; r < TILE / THREADS; ++r) {
        int p = r * THREADS + t;
        if (p < tileCount) {
            uint64_t c = tileS[p];
            uint32_t d = (uint32_t)(c >> SHIFT) & (BINS - 1);
            uint32_t g = writeBase[d] + p;
            if (!LAST) {
                dst[(size_t)g] = c;
            } else if (g >= LB) {        // only selected range is ever read; payload only
                dst32[g] = (uint32_t)c;
            }
        }
    }
}

__global__ void finalize(const uint32_t* __restrict__ pay, const float* __restrict__ td,
                         const float* __restrict__ mxtab, float* __restrict__ out) {
    int g = blockIdx.x * 256 + threadIdx.x;
    if (g >= G_CNT) return;
    uint4 p4 = *(const uint4*)(pay + LB + (size_t)g * 4);
    uint32_t cs[4] = {p4.x, p4.y, p4.z, p4.w};
    float maxmin = -100000.0f;
    int maxindex = -100;
    #pragma unroll
    for (int j = 0; j < 4; ++j) {
        int tp = (int)(cs[j] & 0x1FFFFFu);
        bool re1 = ((cs[j] >> 21) & 1u) != 0u;
        float mx = mxtab[tp];
        bool gt = (mx > maxmin);
        if (re1 == gt) { maxmin = mx; maxindex = tp; }
    }
    int mi = maxindex < 0 ? 0 : maxindex;   // clip lower bound; upper never binds
    float4 row = *(const float4*)(td + (size_t)mi * 4);
    *(float4*)(out + (size_t)g * 4) = row;
}

extern "C" void kernel_launch(void* const* d_in, const int* in_sizes, int n_in,
                              void* d_out, int out_size, void* d_ws, size_t ws_size,
                              hipStream_t stream) {
    const float* td = (const float*)d_in[0];
    const float* nb = (const float*)d_in[1];
    float* out = (float*)d_out;
    uint8_t* ws = (uint8_t*)d_ws;

    // layout: mxtab 6MB | gT (NBLK+1)*2048*4 ~4.01MB | totals 8KB | A 16MB | B 16MB  (~44MB)
    float*    mxtab  = (float*)(ws);
    uint32_t* gT     = (uint32_t*)(ws + (size_t)6  * 1024 * 1024);
    uint32_t* totals = (uint32_t*)(ws + (size_t)11 * 1024 * 1024);
    uint64_t* A      = (uint64_t*)(ws + (size_t)12 * 1024 * 1024);
    uint64_t* B      = (uint64_t*)(ws + (size_t)28 * 1024 * 1024);

    build_all<<<NBLK + NB_MX, THREADS, 0, stream>>>(nb, td, A, mxtab, gT);

    // pass 0: kd bits [0,11)  (code bits 32..42)
    radix_rowscan<<<2048, 64, 0, stream>>>(gT, totals);
    radix_scatter<32, 11, false><<<NBLK, THREADS, 0, stream>>>(A, B, nullptr, gT, totals);

    // pass 1: kd bits [11,22)
    radix_hist<43, 11><<<NBLK, THREADS, 0, stream>>>(B, gT);
    radix_rowscan<<<2048, 64, 0, stream>>>(gT, totals);
    radix_scatter<43, 11, false><<<NBLK, THREADS, 0, stream>>>(B, A, nullptr, gT, totals);

    // pass 2: kd bits [22,32) — slim: payload-only writes into selected range
    radix_hist<54, 10><<<NBLK, THREADS, 0, stream>>>(A, gT);
    radix_rowscan<<<1024, 64, 0, stream>>>(gT, totals);
    radix_scatter<54, 10, true><<<NBLK, THREADS, 0, stream>>>(A, nullptr, (uint32_t*)B, gT, totals);

    finalize<<<(G_CNT + 255) / 256, 256, 0, stream>>>((const uint32_t*)B, td, mxtab, out);
}

// Round 6
// 138.893 us; speedup vs baseline: 3.8927x; 1.2554x over previous
//
#include <hip/hip_runtime.h>
#include <stdint.h>

#define T_ROWS 1500000
#define N_ROWS 2000000
#define N_SEL  1048576
#define G_CNT  (N_SEL/4)
#define LB     (N_ROWS - N_SEL)
#define TILE   4096
#define NBLK   ((N_ROWS + TILE - 1)/TILE)     // 489
#define NBLK1  (NBLK + 1)                      // 490 (row stride; last col = total)
#define THREADS 512
#define WAVES  8
#define WTILE  (TILE/WAVES)                    // 512
#define WROUNDS (WTILE/64)                     // 8
#define BINS   256
#define NB_MX  ((T_ROWS + THREADS - 1)/THREADS)

static_assert((uint64_t)NBLK * TILE >= N_ROWS, "tile coverage");
static_assert(T_ROWS < (1 << 21), "tp fits 21 bits");
static_assert((LB * 4) % 16 == 0, "finalize uint4 alignment");

// code = (descending-orderable key << 32) | (flag!=0 << 21) | tp.
// LSD radix over bits [32,64) is stable -> ties keep original (index-ascending)
// order == jnp.argsort(-bt). Payload carries everything finalize needs.
// build also emits the pass-0 per-tile histogram (kd already in regs) and mxtab.
__global__ __launch_bounds__(THREADS) void build_all(
        const float* __restrict__ nb, const float* __restrict__ td,
        uint64_t* __restrict__ codes, float* __restrict__ mxtab,
        uint32_t* __restrict__ gH) {
    const int b = blockIdx.x;
    if (b >= NBLK) {
        int i = (b - NBLK) * THREADS + threadIdx.x;
        if (i < T_ROWS) {
            float4 r = *(const float4*)(td + (size_t)i * 4);
            mxtab[i] = fmaxf(r.y, fmaxf(r.z, r.w));
        }
        return;
    }
    __shared__ uint32_t h[BINS];
    const int t = threadIdx.x;
    const int lane = t & 63;
    if (t < BINS) h[t] = 0;
    __syncthreads();
    const int base = b * TILE;
    #pragma unroll
    for (int r = 0; r < TILE / THREADS; ++r) {
        int i = base + r * THREADS + t;
        bool active = (i < N_ROWS);
        uint32_t kd = 0;
        if (active) {
            const float* row = nb + (size_t)i * 5;
            uint32_t u = __float_as_uint(row[1]);
            uint32_t ku = (u & 0x80000000u) ? ~u : (u | 0x80000000u); // asc uint == asc float
            kd = ~ku;                                                 // asc uint == desc float
            uint32_t tp = (uint32_t)(int)row[0];                      // exact: integral f32
            uint32_t fl = (row[4] != 0.0f) ? 1u : 0u;
            codes[i] = ((uint64_t)kd << 32) | (fl << 21) | tp;
        }
        uint32_t d = kd & (BINS - 1);       // pass-0 digit
        uint64_t m = __ballot(active ? 1 : 0);
        #pragma unroll
        for (int bb = 0; bb < 8; ++bb) {
            uint64_t x = __ballot((active && ((d >> bb) & 1u)) ? 1 : 0);
            m = ((d >> bb) & 1u) ? (m & x) : (m & ~x);
        }
        int ldr = __ffsll((unsigned long long)m) - 1;
        if (active && lane == ldr) atomicAdd(&h[d], (uint32_t)__popcll(m));
    }
    __syncthreads();
    if (t < BINS) gH[(size_t)t * NBLK1 + b] = h[t];
}

template <int SHIFT>
__global__ __launch_bounds__(THREADS) void radix_hist(
        const uint64_t* __restrict__ src, uint32_t* __restrict__ gH) {
    __shared__ uint32_t h[BINS];
    const int t = threadIdx.x;
    const int lane = t & 63;
    if (t < BINS) h[t] = 0;
    __syncthreads();
    const int base = blockIdx.x * TILE;
    #pragma unroll
    for (int r = 0; r < TILE / THREADS; ++r) {
        int i = base + r * THREADS + t;
        bool active = (i < N_ROWS);
        uint32_t d = active ? ((uint32_t)(src[i] >> SHIFT) & (BINS - 1)) : 0u;
        uint64_t m = __ballot(active ? 1 : 0);
        #pragma unroll
        for (int bb = 0; bb < 8; ++bb) {
            uint64_t x = __ballot((active && ((d >> bb) & 1u)) ? 1 : 0);
            m = ((d >> bb) & 1u) ? (m & x) : (m & ~x);
        }
        int ldr = __ffsll((unsigned long long)m) - 1;
        if (active && lane == ldr) atomicAdd(&h[d], (uint32_t)__popcll(m));
    }
    __syncthreads();
    if (t < BINS) gH[(size_t)t * NBLK1 + blockIdx.x] = h[t];
}

// one block per digit: exclusive scan of contiguous row; total -> row[NBLK] and totals[d]
__global__ void radix_rowscan(uint32_t* __restrict__ gH, uint32_t* __restrict__ totals) {
    const int d = blockIdx.x;
    const int lane = threadIdx.x;
    uint32_t* row = gH + (size_t)d * NBLK1;
    uint32_t carry = 0;
    for (int b0 = 0; b0 < NBLK; b0 += 64) {
        int i = b0 + lane;
        uint32_t v = (i < NBLK) ? row[i] : 0u;
        uint32_t s = v;
        for (int off = 1; off < 64; off <<= 1) {
            uint32_t tt = __shfl_up(s, off, 64);
            if (lane >= off) s += tt;
        }
        if (i < NBLK) row[i] = s - v + carry;
        carry += __shfl(s, 63, 64);
    }
    if (lane == 0) {
        row[NBLK] = carry;
        totals[d] = carry;
    }
}

template <int SHIFT, bool LAST>
__global__ __launch_bounds__(THREADS) void radix_scatter(
        const uint64_t* __restrict__ src, uint64_t* __restrict__ dst,
        uint32_t* __restrict__ dst32,
        const uint32_t* __restrict__ gH, const uint32_t* __restrict__ totals) {
    __shared__ uint64_t tileS[TILE];             // 32 KB
    __shared__ uint32_t cnt32[BINS * WAVES];     // 8 KB  per-(digit,wave) counts/cursors
    __shared__ uint32_t writeBase[BINS];
    __shared__ uint32_t lstart[BINS];
    const int t = threadIdx.x;
    const int lane = t & 63;
    const int w = t >> 6;
    const int blk = blockIdx.x;
    const int base = blk * TILE;
    const int tileCount = (N_ROWS - base < TILE) ? (N_ROWS - base) : TILE;

    #pragma unroll
    for (int k = t; k < BINS * WAVES; k += THREADS) cnt32[k] = 0u;
    __syncthreads();

    // ---- phase A: per-wave digit counts via ballot match; save (rank,ldr,cnt) per round
    uint64_t creg[WROUNDS];
    uint32_t meta[WROUNDS];
    const uint64_t below = (lane == 0) ? 0ull : (~0ull >> (64 - lane));
    #pragma unroll
    for (int r = 0; r < WROUNDS; ++r) {
        int idx = base + w * WTILE + r * 64 + lane;
        bool active = (idx < N_ROWS);
        uint64_t c = active ? src[idx] : 0ull;
        creg[r] = c;
        uint32_t d = (uint32_t)(c >> SHIFT) & (BINS - 1);
        uint64_t m = __ballot(active ? 1 : 0);
        #pragma unroll
        for (int bb = 0; bb < 8; ++bb) {
            uint64_t x = __ballot((active && ((d >> bb) & 1u)) ? 1 : 0);
            m = ((d >> bb) & 1u) ? (m & x) : (m & ~x);
        }
        int ldr = __ffsll((unsigned long long)m) - 1;
        uint32_t cnt = (uint32_t)__popcll(m);
        uint32_t rank = (uint32_t)__popcll(m & below);
        meta[r] = rank | ((uint32_t)(ldr < 0 ? 0 : ldr) << 8) | (cnt << 16);
        if (active && lane == ldr)
            atomicAdd(&cnt32[d * WAVES + w], cnt);
    }
    __syncthreads();

    // ---- phase B1: wave 0 (4 digits/lane): writeBase[d], lstart[d]
    if (t < 64) {
        uint32_t tot[4], rp[4], lc[4];
        uint32_t sumT = 0, sumL = 0;
        #pragma unroll
        for (int k = 0; k < 4; ++k) {
            int d = t * 4 + k;
            tot[k] = totals[d];
            rp[k] = gH[(size_t)d * NBLK1 + blk];
            lc[k] = gH[(size_t)d * NBLK1 + blk + 1] - rp[k];
            sumT += tot[k]; sumL += lc[k];
        }
        uint32_t sT = sumT, sL = sumL;
        for (int off = 1; off < 64; off <<= 1) {
            uint32_t aT = __shfl_up(sT, off, 64);
            uint32_t aL = __shfl_up(sL, off, 64);
            if (t >= off) { sT += aT; sL += aL; }
        }
        uint32_t exT = sT - sumT, exL = sL - sumL;
        #pragma unroll
        for (int k = 0; k < 4; ++k) {
            int d = t * 4 + k;
            writeBase[d] = exT + rp[k] - exL;
            lstart[d] = exL;
            exT += tot[k]; exL += lc[k];
        }
    }
    __syncthreads();

    // ---- phase B2: cursors = tile-local digit start + cross-wave prefix
    if (t < BINS) {
        uint32_t run = lstart[t];
        #pragma unroll
        for (int wv = 0; wv < WAVES; ++wv) {
            uint32_t c0 = cnt32[t * WAVES + wv];
            cnt32[t * WAVES + wv] = run;
            run += c0;
        }
    }
    __syncthreads();

    // ---- phase C: ballot-free — leader atomicAdd on cursor, shfl, LDS scatter
    #pragma unroll
    for (int r = 0; r < WROUNDS; ++r) {
        int idx = base + w * WTILE + r * 64 + lane;
        bool active = (idx < N_ROWS);
        uint64_t c = creg[r];
        uint32_t d = (uint32_t)(c >> SHIFT) & (BINS - 1);
        uint32_t mt = meta[r];
        uint32_t rank = mt & 0xFFu;
        int ldr = (int)((mt >> 8) & 0xFFu);
        uint32_t cnt = mt >> 16;
        uint32_t before = 0;
        if (active && lane == ldr)
            before = atomicAdd(&cnt32[d * WAVES + w], cnt);
        before = __shfl(before, ldr, 64);
        if (active) tileS[before + rank] = c;
    }
    __syncthreads();

    // ---- write-out: consecutive sorted positions share digit -> 128B avg segments
    #pragma unroll
    for (int r = 0; r < TILE / THREADS; ++r) {
        int p = r * THREADS + t;
        if (p < tileCount) {
            uint64_t c = tileS[p];
            uint32_t d = (uint32_t)(c >> SHIFT) & (BINS - 1);
            uint32_t g = writeBase[d] + p;
            if (!LAST) {
                dst[(size_t)g] = c;
            } else if (g >= LB) {        // only selected range is read; payload only
                dst32[g] = (uint32_t)c;
            }
        }
    }
}

__global__ void finalize(const uint32_t* __restrict__ pay, const float* __restrict__ td,
                         const float* __restrict__ mxtab, float* __restrict__ out) {
    int g = blockIdx.x * 256 + threadIdx.x;
    if (g >= G_CNT) return;
    uint4 p4 = *(const uint4*)(pay + LB + (size_t)g * 4);
    uint32_t cs[4] = {p4.x, p4.y, p4.z, p4.w};
    float maxmin = -100000.0f;
    int maxindex = -100;
    #pragma unroll
    for (int j = 0; j < 4; ++j) {
        int tp = (int)(cs[j] & 0x1FFFFFu);
        bool re1 = ((cs[j] >> 21) & 1u) != 0u;
        float mx = mxtab[tp];
        bool gt = (mx > maxmin);
        if (re1 == gt) { maxmin = mx; maxindex = tp; }
    }
    int mi = maxindex < 0 ? 0 : maxindex;   // clip lower bound; upper never binds
    float4 row = *(const float4*)(td + (size_t)mi * 4);
    *(float4*)(out + (size_t)g * 4) = row;
}

extern "C" void kernel_launch(void* const* d_in, const int* in_sizes, int n_in,
                              void* d_out, int out_size, void* d_ws, size_t ws_size,
                              hipStream_t stream) {
    const float* td = (const float*)d_in[0];
    const float* nb = (const float*)d_in[1];
    float* out = (float*)d_out;
    uint8_t* ws = (uint8_t*)d_ws;

    // layout: mxtab 6MB | gH 256*490*4 ~0.5MB | totals 1KB | A 16MB | B 16MB (~40MB)
    float*    mxtab  = (float*)(ws);
    uint32_t* gH     = (uint32_t*)(ws + (size_t)6 * 1024 * 1024);
    uint32_t* totals = (uint32_t*)(ws + (size_t)7 * 1024 * 1024);
    uint64_t* A      = (uint64_t*)(ws + (size_t)8 * 1024 * 1024);
    uint64_t* B      = (uint64_t*)(ws + (size_t)24 * 1024 * 1024);

    build_all<<<NBLK + NB_MX, THREADS, 0, stream>>>(nb, td, A, mxtab, gH);

    // pass 0: code bits [32,40) — histogram fused into build
    radix_rowscan<<<BINS, 64, 0, stream>>>(gH, totals);
    radix_scatter<32, false><<<NBLK, THREADS, 0, stream>>>(A, B, nullptr, gH, totals);

    // pass 1: bits [40,48)
    radix_hist<40><<<NBLK, THREADS, 0, stream>>>(B, gH);
    radix_rowscan<<<BINS, 64, 0, stream>>>(gH, totals);
    radix_scatter<40, false><<<NBLK, THREADS, 0, stream>>>(B, A, nullptr, gH, totals);

    // pass 2: bits [48,56)
    radix_hist<48><<<NBLK, THREADS, 0, stream>>>(A, gH);
    radix_rowscan<<<BINS, 64, 0, stream>>>(gH, totals);
    radix_scatter<48, false><<<NBLK, THREADS, 0, stream>>>(A, B, nullptr, gH, totals);

    // pass 3: bits [56,64) — slim: payload-only u32 writes into selected range
    radix_hist<56><<<NBLK, THREADS, 0, stream>>>(B, gH);
    radix_rowscan<<<BINS, 64, 0, stream>>>(gH, totals);
    radix_scatter<56, true><<<NBLK, THREADS, 0, stream>>>(B, nullptr, (uint32_t*)A, gH, totals);

    finalize<<<(G_CNT + 255) / 256, 256, 0, stream>>>((const uint32_t*)A, td, mxtab, out);
}